// Round 1
// baseline (1353.094 us; speedup 1.0000x reference)
//
#include <hip/hip_runtime.h>

#define NN 100000
#define DEG 16
#define HEADS 4
#define NEG_SLOPE 0.2f

// ---------------- GEMM: C[M,Nc] = A[M,K] * W[K,Nc], fp32, row-major ----------
#define BM 64
#define BN 64
#define BK 32

__global__ __launch_bounds__(256) void gemm_f32(
    const float* __restrict__ A, const float* __restrict__ W,
    float* __restrict__ C, int M, int K, int Nc)
{
    __shared__ float As[BK][BM + 1];   // transposed, padded
    __shared__ float Bs[BK][BN];

    const int tid = threadIdx.x;            // 256 threads
    const int tx = tid & 15;                // 0..15 -> col group
    const int ty = tid >> 4;                // 0..15 -> row group
    const int row0 = blockIdx.y * BM;
    const int col0 = blockIdx.x * BN;

    float acc[4][4] = {};

    for (int k0 = 0; k0 < K; k0 += BK) {
        // Load A tile: 64 rows x 32 cols (float4 per thread, 2 passes)
        #pragma unroll
        for (int p = 0; p < 2; ++p) {
            int r = p * 32 + (tid >> 3);        // 0..63
            int c = (tid & 7) * 4;              // 0..28
            float4 v = make_float4(0.f, 0.f, 0.f, 0.f);
            int gr = row0 + r;
            if (gr < M)
                v = *reinterpret_cast<const float4*>(&A[(size_t)gr * K + k0 + c]);
            As[c + 0][r] = v.x;
            As[c + 1][r] = v.y;
            As[c + 2][r] = v.z;
            As[c + 3][r] = v.w;
        }
        // Load B tile: 32 rows x 64 cols
        #pragma unroll
        for (int p = 0; p < 2; ++p) {
            int r = p * 16 + (tid >> 4);        // 0..31
            int c = (tid & 15) * 4;             // 0..60
            float4 v = make_float4(0.f, 0.f, 0.f, 0.f);
            if (col0 + c < Nc)                  // Nc % 4 == 0 so all-or-nothing
                v = *reinterpret_cast<const float4*>(&W[(size_t)(k0 + r) * Nc + col0 + c]);
            *reinterpret_cast<float4*>(&Bs[r][c]) = v;
        }
        __syncthreads();

        #pragma unroll
        for (int k = 0; k < BK; ++k) {
            float a[4];
            #pragma unroll
            for (int i = 0; i < 4; ++i) a[i] = As[k][ty * 4 + i];
            float4 bv = *reinterpret_cast<const float4*>(&Bs[k][tx * 4]);
            float b[4] = {bv.x, bv.y, bv.z, bv.w};
            #pragma unroll
            for (int i = 0; i < 4; ++i)
                #pragma unroll
                for (int j = 0; j < 4; ++j)
                    acc[i][j] += a[i] * b[j];
        }
        __syncthreads();
    }

    // Store (float4 per row; Nc % 4 == 0 keeps this all-or-nothing valid)
    const int gc0 = col0 + tx * 4;
    #pragma unroll
    for (int i = 0; i < 4; ++i) {
        int gr = row0 + ty * 4 + i;
        if (gr < M && gc0 < Nc) {
            float4 st = make_float4(acc[i][0], acc[i][1], acc[i][2], acc[i][3]);
            *reinterpret_cast<float4*>(&C[(size_t)gr * Nc + gc0]) = st;
        }
    }
}

// ---------------- scores: el[n,h] = sum_d feat[n,h*D+d]*al[h*D+d] ------------
__global__ __launch_bounds__(256) void scores_kernel(
    const float* __restrict__ feat, const float* __restrict__ al,
    const float* __restrict__ ar, float* __restrict__ el, float* __restrict__ er,
    int D, int HD)
{
    const int n = blockIdx.x;
    const int t = threadIdx.x;
    const int h = t >> 6;       // wave id = head
    const int j = t & 63;
    float v = 0.f, u = 0.f;
    if (j < D) {
        float f = feat[(size_t)n * HD + h * D + j];
        v = f * al[h * D + j];
        u = f * ar[h * D + j];
    }
    #pragma unroll
    for (int off = 32; off > 0; off >>= 1) {
        v += __shfl_down(v, off);
        u += __shfl_down(u, off);
    }
    if (j == 0) {
        el[n * HEADS + h] = v;
        er[n * HEADS + h] = u;
    }
}

// ---------------- aggregation, full-width layers (HD = 256) -----------------
__global__ __launch_bounds__(256) void agg_full(
    const float* __restrict__ feat, const float* __restrict__ el,
    const float* __restrict__ er, const int* __restrict__ col,
    float* __restrict__ out)
{
    __shared__ int   s_src[DEG];
    __shared__ float s_a[HEADS][DEG];

    const int n = blockIdx.x;
    const int t = threadIdx.x;

    if (t < DEG) s_src[t] = col[n * DEG + t];
    __syncthreads();

    if (t < HEADS * DEG) {
        int h = t >> 4, k = t & 15;
        float x = el[s_src[k] * HEADS + h] + er[n * HEADS + h];
        s_a[h][k] = x > 0.f ? x : NEG_SLOPE * x;
    }
    __syncthreads();

    if (t < HEADS) {
        float m = -1e30f;
        #pragma unroll
        for (int k = 0; k < DEG; ++k) m = fmaxf(m, s_a[t][k]);
        float s = 0.f;
        #pragma unroll
        for (int k = 0; k < DEG; ++k) {
            float ex = __expf(s_a[t][k] - m);
            s += ex;
            s_a[t][k] = ex;
        }
        float inv = 1.f / s;
        #pragma unroll
        for (int k = 0; k < DEG; ++k) s_a[t][k] *= inv;
    }
    __syncthreads();

    const int h = t >> 6;
    float acc = 0.f;
    #pragma unroll
    for (int k = 0; k < DEG; ++k)
        acc += s_a[h][k] * feat[(size_t)s_src[k] * 256 + t];
    out[(size_t)n * 256 + t] = acc;
}

// ---------------- aggregation, output layer (HD = 164, mean over heads) -----
__global__ __launch_bounds__(256) void agg_out(
    const float* __restrict__ feat, const float* __restrict__ el,
    const float* __restrict__ er, const int* __restrict__ col,
    float* __restrict__ out)   // out: [N, 41]
{
    __shared__ int   s_src[DEG];
    __shared__ float s_a[HEADS][DEG];
    __shared__ float s_agg[HEADS * 41];

    const int n = blockIdx.x;
    const int t = threadIdx.x;

    if (t < DEG) s_src[t] = col[n * DEG + t];
    __syncthreads();

    if (t < HEADS * DEG) {
        int h = t >> 4, k = t & 15;
        float x = el[s_src[k] * HEADS + h] + er[n * HEADS + h];
        s_a[h][k] = x > 0.f ? x : NEG_SLOPE * x;
    }
    __syncthreads();

    if (t < HEADS) {
        float m = -1e30f;
        #pragma unroll
        for (int k = 0; k < DEG; ++k) m = fmaxf(m, s_a[t][k]);
        float s = 0.f;
        #pragma unroll
        for (int k = 0; k < DEG; ++k) {
            float ex = __expf(s_a[t][k] - m);
            s += ex;
            s_a[t][k] = ex;
        }
        float inv = 1.f / s;
        #pragma unroll
        for (int k = 0; k < DEG; ++k) s_a[t][k] *= inv;
    }
    __syncthreads();

    if (t < HEADS * 41) {
        int h = t / 41;
        float acc = 0.f;
        #pragma unroll
        for (int k = 0; k < DEG; ++k)
            acc += s_a[h][k] * feat[(size_t)s_src[k] * 164 + t];
        s_agg[t] = acc;
    }
    __syncthreads();

    if (t < 41)
        out[(size_t)n * 41 + t] =
            0.25f * (s_agg[t] + s_agg[t + 41] + s_agg[t + 82] + s_agg[t + 123]);
}

extern "C" void kernel_launch(void* const* d_in, const int* in_sizes, int n_in,
                              void* d_out, int out_size, void* d_ws, size_t ws_size,
                              hipStream_t stream)
{
    const int*   col_ind = (const int*)  d_in[1];
    const float* inputs  = (const float*)d_in[2];
    const float* W0      = (const float*)d_in[3];
    const float* al0     = (const float*)d_in[4];
    const float* ar0     = (const float*)d_in[5];
    const float* W1      = (const float*)d_in[6];
    const float* al1     = (const float*)d_in[7];
    const float* ar1     = (const float*)d_in[8];
    const float* W2      = (const float*)d_in[9];
    const float* al2     = (const float*)d_in[10];
    const float* ar2     = (const float*)d_in[11];
    float* out = (float*)d_out;

    char* ws = (char*)d_ws;
    const size_t featBytes = (size_t)NN * 256 * sizeof(float);
    float* featA = (float*)ws;                          // [N,256] (or [N,164])
    float* hB    = (float*)(ws + featBytes);            // [N,256]
    float* el    = (float*)(ws + 2 * featBytes);        // [N,4]
    float* er    = el + (size_t)NN * HEADS;             // [N,4]

    dim3 blk(256);
    dim3 g256(4, (NN + BM - 1) / BM);
    dim3 g164(3, (NN + BM - 1) / BM);

    // Layer 0
    gemm_f32<<<g256, blk, 0, stream>>>(inputs, W0, featA, NN, 256, 256);
    scores_kernel<<<NN, blk, 0, stream>>>(featA, al0, ar0, el, er, 64, 256);
    agg_full<<<NN, blk, 0, stream>>>(featA, el, er, col_ind, hB);

    // Layer 1
    gemm_f32<<<g256, blk, 0, stream>>>(hB, W1, featA, NN, 256, 256);
    scores_kernel<<<NN, blk, 0, stream>>>(featA, al1, ar1, el, er, 64, 256);
    agg_full<<<NN, blk, 0, stream>>>(featA, el, er, col_ind, hB);

    // Layer 2
    gemm_f32<<<g164, blk, 0, stream>>>(hB, W2, featA, NN, 256, 164);
    scores_kernel<<<NN, blk, 0, stream>>>(featA, al2, ar2, el, er, 41, 164);
    agg_out<<<NN, blk, 0, stream>>>(featA, el, er, col_ind, out);
}